// Round 2
// baseline (378.069 us; speedup 1.0000x reference)
//
#include <hip/hip_runtime.h>

// SGIntoKGPool: out[b,m,c] = (sum_n adj[b,n,m] * x[b,c,n]) / max(sum_n adj[b,n,m], 1)
// fp32 in / fp32 out. Internal compute: bf16 MFMA 16x16x32 with f32 accumulation
// (2% relative threshold permits this; degrees accumulated in exact fp32).
//
// Tiling: block = (bz, 64-wide m slice). 512 threads = 8 waves, wave = 32m x 16c.
// adj tile (64n x 64m fp32) is transposed+converted into LDS bf16 with a
// bank-conflict-free swizzle:
//   element (m, nl) -> dword 36*m + 4*((nl>>3) ^ ((m>>2)&7)) + ((nl&7)>>1), half nl&1
//   (row stride 36 dw => +4*(m&7) bank term; XOR at 16B granularity keeps
//    ds_read_b128 fragment reads 16-B aligned and conflict-free.)
// x B-fragments load fp32 directly from global (L2-resident) and pack to bf16.
// Degrees accumulated inline (fp32) during staging, reduced via LDS atomics.

typedef short bf16x8 __attribute__((ext_vector_type(8)));
typedef float f32x4 __attribute__((ext_vector_type(4)));

#define BZc 8
#define Cc 64
#define Nc 4096
#define Mc 2048
#define BMc 64
#define BKc 64
#define KITERS (Nc / BKc)   // 64
#define SDW 36              // adjT row stride in dwords (144 B, 16B-aligned)

// pack two fp32 -> dword with low16 = bf16(a), high16 = bf16(b); +0x8000 = round-to-nearest
__device__ __forceinline__ unsigned int pkbf(float a, float b) {
  unsigned int ua = __float_as_uint(a) + 0x8000u;
  unsigned int ub = __float_as_uint(b) + 0x8000u;
  return (ua >> 16) | (ub & 0xffff0000u);
}

__global__ __launch_bounds__(512) void sgkg_kernel(
    const float* __restrict__ x,     // (BZ, C, N) fp32
    const float* __restrict__ adj,   // (BZ, N, M) fp32
    float* __restrict__ out)         // (BZ, M, C) fp32
{
  __shared__ unsigned int adjT[BMc * SDW];    // 9216 B
  __shared__ float degs[BMc];

  const int t = threadIdx.x;
  const int l = t & 63;
  const int w = t >> 6;

  const int bz     = blockIdx.x >> 5;         // 32 m-blocks per batch
  const int m_base = (blockIdx.x & 31) * BMc;

  // ---- staging mapping: thread -> (mg: 4-m group, p: n-row pair) ----
  const int mg  = ((w & 1) << 3) | (l & 7);   // 0..15
  const int p   = ((w >> 1) << 3) | (l >> 3); // 0..31
  const int sm0 = mg << 2;                    // local m of first of 4 values

  const float* aptr =
      adj + (size_t)bz * Nc * Mc + (size_t)(2 * p) * Mc + (m_base + sm0);
  // write base dword: j-th write goes to wb + j*SDW (m = sm0+j)
  const int wb = SDW * sm0 + ((((p >> 2) ^ (mg & 7))) << 2) + (p & 3);

  // ---- compute mapping: wave = 32m x 16c ----
  const int m_off = (w & 1) << 5;   // 0 or 32
  const int c_b   = (w >> 1) << 4;  // 0,16,32,48
  const int l15   = l & 15;
  const int l4    = l >> 4;

  // B-fragment global base: row c = c_b + l15, k offset l4*8
  const float* xb =
      x + ((size_t)bz * Cc + (c_b + l15)) * Nc + (l4 << 3);

  // A-fragment LDS dword addresses, per (tm, kstep)
  int aaddr[2][2];
#pragma unroll
  for (int tm = 0; tm < 2; ++tm) {
    const int m  = m_off + tm * 16 + l15;
    const int pi = (m >> 2) & 7;
    aaddr[tm][0] = SDW * m + (((l4) ^ pi) << 2);
    aaddr[tm][1] = SDW * m + (((4 + l4) ^ pi) << 2);
  }

  if (t < BMc) degs[t] = 0.0f;

  f32x4 acc0 = {0.f, 0.f, 0.f, 0.f};
  f32x4 acc1 = {0.f, 0.f, 0.f, 0.f};
  float dacc0 = 0.f, dacc1 = 0.f, dacc2 = 0.f, dacc3 = 0.f;

  // prefetch first adj tile (2 n-rows x 4 m, fp32)
  float4 r0 = *(const float4*)aptr;
  float4 r1 = *(const float4*)(aptr + Mc);

  for (int it = 0; it < KITERS; ++it) {
    __syncthreads();  // previous iter done reading adjT (also covers degs init)

    // ---- stage transposed+converted: dword = (bf16 adj[n][m], bf16 adj[n+1][m]) ----
    adjT[wb          ] = pkbf(r0.x, r1.x);
    adjT[wb +     SDW] = pkbf(r0.y, r1.y);
    adjT[wb + 2 * SDW] = pkbf(r0.z, r1.z);
    adjT[wb + 3 * SDW] = pkbf(r0.w, r1.w);

    // ---- degrees (exact fp32) for the 4 m's this thread stages ----
    dacc0 += r0.x + r1.x;
    dacc1 += r0.y + r1.y;
    dacc2 += r0.z + r1.z;
    dacc3 += r0.w + r1.w;

    // ---- prefetch next adj tile (dummy re-read on last iter) ----
    const float* anext = (it + 1 < KITERS) ? (aptr + (size_t)BKc * Mc) : aptr;
    float4 s0 = *(const float4*)anext;
    float4 s1 = *(const float4*)(anext + Mc);

    // ---- B fragments for this iter (global fp32 -> packed bf16) ----
    const float* xit = xb + it * BKc;
    float4 blo0 = *(const float4*)(xit);
    float4 bhi0 = *(const float4*)(xit + 4);
    float4 blo1 = *(const float4*)(xit + 32);
    float4 bhi1 = *(const float4*)(xit + 36);
    union { uint4 u; bf16x8 v; } B0, B1;
    B0.u = make_uint4(pkbf(blo0.x, blo0.y), pkbf(blo0.z, blo0.w),
                      pkbf(bhi0.x, bhi0.y), pkbf(bhi0.z, bhi0.w));
    B1.u = make_uint4(pkbf(blo1.x, blo1.y), pkbf(blo1.z, blo1.w),
                      pkbf(bhi1.x, bhi1.y), pkbf(bhi1.z, bhi1.w));

    __syncthreads();  // adjT writes visible

    // ---- MFMA: 2 m-tiles x 2 k-steps ----
    bf16x8 a00 = *(const bf16x8*)(adjT + aaddr[0][0]);
    bf16x8 a10 = *(const bf16x8*)(adjT + aaddr[1][0]);
    acc0 = __builtin_amdgcn_mfma_f32_16x16x32_bf16(a00, B0.v, acc0, 0, 0, 0);
    acc1 = __builtin_amdgcn_mfma_f32_16x16x32_bf16(a10, B0.v, acc1, 0, 0, 0);
    bf16x8 a01 = *(const bf16x8*)(adjT + aaddr[0][1]);
    bf16x8 a11 = *(const bf16x8*)(adjT + aaddr[1][1]);
    acc0 = __builtin_amdgcn_mfma_f32_16x16x32_bf16(a01, B1.v, acc0, 0, 0, 0);
    acc1 = __builtin_amdgcn_mfma_f32_16x16x32_bf16(a11, B1.v, acc1, 0, 0, 0);

    aptr = anext;
    r0 = s0;
    r1 = s1;
  }

  // ---- degree reduction ----
  __syncthreads();
  atomicAdd(&degs[sm0 + 0], dacc0);
  atomicAdd(&degs[sm0 + 1], dacc1);
  atomicAdd(&degs[sm0 + 2], dacc2);
  atomicAdd(&degs[sm0 + 3], dacc3);
  __syncthreads();

  // ---- epilogue: normalize + fp32 store ----
  // D layout (16x16x32): col = l&15 (c), row = (l>>4)*4 + r (m)
#pragma unroll
  for (int tm = 0; tm < 2; ++tm) {
    const f32x4 acc = tm ? acc1 : acc0;
#pragma unroll
    for (int r = 0; r < 4; ++r) {
      const int ml    = m_off + tm * 16 + (l4 << 2) + r;
      const float nrm = fmaxf(degs[ml], 1.0f);
      const float v   = acc[r] / nrm;
      const size_t o  = ((size_t)(bz * Mc + m_base + ml)) * Cc + (c_b + l15);
      out[o] = v;
    }
  }
}

extern "C" void kernel_launch(void* const* d_in, const int* in_sizes, int n_in,
                              void* d_out, int out_size, void* d_ws, size_t ws_size,
                              hipStream_t stream) {
  const float* x   = (const float*)d_in[0];  // sg_node_feats (8,64,64,64) fp32
  const float* adj = (const float*)d_in[1];  // sg_kg_adj (8,4096,2048) fp32
  float* out       = (float*)d_out;          // (8,2048,64) fp32
  (void)in_sizes; (void)n_in; (void)out_size; (void)d_ws; (void)ws_size;

  sgkg_kernel<<<dim3(BZc * (Mc / BMc)), dim3(512), 0, stream>>>(x, adj, out);
}